// Round 11
// baseline (2395.110 us; speedup 1.0000x reference)
//
#include <hip/hip_runtime.h>
#include <cstdint>

typedef _Float16 f16;
typedef _Float16 f16x8 __attribute__((ext_vector_type(8)));
typedef float f32x4 __attribute__((ext_vector_type(4)));
typedef unsigned int u32;

#define DEV __device__ __forceinline__

DEV void gll16(const void* g, void* l) {
  __builtin_amdgcn_global_load_lds((const __attribute__((address_space(1))) u32*)g,
                                   (__attribute__((address_space(3))) u32*)l, 16, 0, 0);
}

DEV float wsum(float v) {
#pragma unroll
  for (int o = 32; o; o >>= 1) v += __shfl_xor(v, o);
  return v;
}

// fragment-linear weight index: B''[(n>>4)*KS8 + (k>>3)][ (n&15)*8 + (k&7) ]
DEV size_t fidx(int n, int k, int KS8) {
  return ((size_t)(n >> 4) * KS8 + (k >> 3)) * 128 + (n & 15) * 8 + (k & 7);
}

// ---------------- GEMM 128x128 (QKV / FC): BK=64, dbuf LDS, counted vmcnt ----------------
// EPI 1: QKV -> qhat/khat/vT.   EPI 2: bias+gelu -> H1 + atomicAdd ssq.
template <int EPI>
__global__ __launch_bounds__(512)
void k_gemm(const f16* __restrict__ A, const f16* __restrict__ B, int GM,
            const float* __restrict__ c0, const float* __restrict__ c1,
            const float* __restrict__ c2, float* __restrict__ ssq,
            f16* __restrict__ H1, f16* __restrict__ H2, f16* __restrict__ H3) {
  const int tid = threadIdx.x, wid = tid >> 6, lane = tid & 63;
  const int l15 = lane & 15, l4 = lane >> 4;
  const int wm = wid % 4, wn = wid / 4;
  const int nwg = gridDim.x;
  int lin = blockIdx.x;
  int wg = (lin & 7) * (nwg >> 3) + (lin >> 3);
  int tn = wg / GM, tm = wg - tn * GM;
  const int m0 = tm * 128, n0 = tn * 128;
  __shared__ __align__(16) char SM[256 * 256];
  f32x4 acc[2][4];
#pragma unroll
  for (int i = 0; i < 2; i++)
#pragma unroll
    for (int j = 0; j < 4; j++) acc[i][j] = (f32x4){0.f, 0.f, 0.f, 0.f};
  const size_t ldab = 1024;  // lda = 512 f16
  const int swz = ((lane & 7) ^ (lane >> 3)) * 16;
  const char* Ab = (const char*)A + (size_t)(m0 + (lane >> 3)) * ldab + swz;
  const char* Bb = (const char*)B + (size_t)(n0 + (lane >> 3)) * ldab + swz;
  auto stage = [&](int buf, int ks) {  // 4 gll16 per wave
    char* da = SM + buf * 16384;
    char* db = SM + 32768 + buf * 16384;
    for (int i = wid; i < 16; i += 8)
      gll16(Ab + (size_t)(i * 8) * ldab + (size_t)ks * 128, da + i * 1024);
    for (int i = wid; i < 16; i += 8)
      gll16(Bb + (size_t)(i * 8) * ldab + (size_t)ks * 128, db + i * 1024);
  };
  stage(0, 0);
  asm volatile("s_waitcnt vmcnt(0)" ::: "memory");
  __builtin_amdgcn_s_barrier();
  __builtin_amdgcn_sched_barrier(0);
  int cur = 0;
  for (int ks = 0; ks < 8; ks++) {
    const bool more = (ks + 1 < 8);
    if (more) {
      stage(cur ^ 1, ks + 1);
      asm volatile("s_waitcnt vmcnt(4)" ::: "memory");
    } else {
      asm volatile("s_waitcnt vmcnt(0)" ::: "memory");
    }
    __builtin_amdgcn_s_barrier();
    __builtin_amdgcn_sched_barrier(0);
    const f16* sA = (const f16*)(SM + cur * 16384);
    const f16* sB = (const f16*)(SM + 32768 + cur * 16384);
#pragma unroll
    for (int kk = 0; kk < 2; kk++) {
      f16x8 af[2], bf[4];
#pragma unroll
      for (int i = 0; i < 2; i++) {
        int row = wm * 32 + i * 16 + l15;
        af[i] = *(const f16x8*)(sA + row * 64 + (((kk * 4 + l4) ^ (l15 & 7)) * 8));
      }
#pragma unroll
      for (int j = 0; j < 4; j++) {
        int row = wn * 64 + j * 16 + l15;
        bf[j] = *(const f16x8*)(sB + row * 64 + (((kk * 4 + l4) ^ (l15 & 7)) * 8));
      }
#pragma unroll
      for (int i = 0; i < 2; i++)
#pragma unroll
        for (int j = 0; j < 4; j++)
          acc[i][j] = __builtin_amdgcn_mfma_f32_16x16x32_f16(af[i], bf[j], acc[i][j], 0, 0, 0);
    }
    __builtin_amdgcn_sched_barrier(0);
    __builtin_amdgcn_s_barrier();
    cur ^= 1;
  }
  if (EPI == 1) {
    const int cb = (n0 >> 6) + wn;
    const int typ = cb >> 3, h = cb & 7;
    const float* bb = (typ == 0) ? c0 : (typ == 1) ? c1 : c2;
    float bj[4];
#pragma unroll
    for (int j = 0; j < 4; j++) bj[j] = bb[h * 64 + j * 16 + l15];
    const float qs = (typ == 0) ? 0.25f : 1.0f;
#pragma unroll
    for (int i = 0; i < 2; i++) {
#pragma unroll
      for (int r = 0; r < 4; r++) {
        float y[4], ss = 0.f;
#pragma unroll
        for (int j = 0; j < 4; j++) { y[j] = acc[i][j][r] + bj[j]; ss += y[j] * y[j]; }
        ss += __shfl_xor(ss, 1); ss += __shfl_xor(ss, 2);
        ss += __shfl_xor(ss, 4); ss += __shfl_xor(ss, 8);
        float t = sqrtf(ss + 1.f);
        int row = m0 + wm * 32 + i * 16 + l4 * 4 + r;
        int b = row >> 10, s = row & 1023, bh = b * 8 + h;
        if (typ < 2) {
          f16* dst = typ ? H2 : H1;
          size_t base = ((size_t)bh * 1024 + s) * 88;
#pragma unroll
          for (int j = 0; j < 4; j++) dst[base + j * 16 + l15] = (f16)(qs * y[j]);
          if (l15 == 0) dst[base + 64] = (f16)(qs * t);
        } else {
#pragma unroll
          for (int j = 0; j < 4; j++)
            H3[((size_t)bh * 80 + j * 16 + l15) * 1024 + s] = (f16)y[j];
          if (l15 == 0) H3[((size_t)bh * 80 + 64) * 1024 + s] = (f16)t;
        }
      }
    }
  } else {
#pragma unroll
    for (int i = 0; i < 2; i++) {
#pragma unroll
      for (int r = 0; r < 4; r++) {
        int row = m0 + wm * 32 + i * 16 + l4 * 4 + r;
        float ss = 0.f;
#pragma unroll
        for (int j = 0; j < 4; j++) {
          int col = n0 + wn * 64 + j * 16 + l15;
          float gg = 0.f;
          if (col < 2047) {
            float yv = acc[i][j][r] + c0[col];
            float cc = yv * yv * yv;
            gg = 0.5f * yv * (1.f + tanhf(0.7978845608f * (yv + 0.044715f * cc)));
          }
          ss += gg * gg;
          H1[(size_t)row * 2048 + col] = (f16)gg;
        }
        ss += __shfl_xor(ss, 1); ss += __shfl_xor(ss, 2);
        ss += __shfl_xor(ss, 4); ss += __shfl_xor(ss, 8);
        if (l15 == 0) atomicAdd(ssq + row, ss);
      }
    }
  }
}

// ---------------- full-row GEMM (BM=16, N=512) + fused resproj / final LN ----------------
// MODE 1: res1 (y=acc+bias; x: xin->xout rw; LN g/bsh -> actW)
// MODE 2: res2 (y=acc+bias+t(ssq)*w0; x update; opt LN -> actW; zero ssq)
// MODE 3: final (y=acc+bias; LN -> outp)
template <int KS, int MODE>
__global__ __launch_bounds__(512)
void k_rowgemm(const f16* __restrict__ A, const f16* __restrict__ B, int lda,
               const float* __restrict__ bias, const float* __restrict__ w0,
               float* __restrict__ ssq, const float* __restrict__ xin,
               float* __restrict__ xout, const float* __restrict__ g,
               const float* __restrict__ bsh, const float* __restrict__ rwv, int li,
               int applyLN, f16* __restrict__ actW, float* __restrict__ outp) {
  const int tid = threadIdx.x, wid = tid >> 6, lane = tid & 63;
  const int l15 = lane & 15, l4 = lane >> 4;
  const int lin = blockIdx.x;
  const int wg = (lin & 7) * 16 + (lin >> 3);  // 128 blocks, XCD-chunked
  const int m0 = wg * 16;
  __shared__ __align__(16) char SMa[4096];      // A dbuf 2 x 2KB
  __shared__ __align__(16) float SC[16 * 520];  // C stage
  f32x4 acc[4];
#pragma unroll
  for (int j = 0; j < 4; j++) acc[j] = (f32x4){0.f, 0.f, 0.f, 0.f};
  const size_t ldab = (size_t)lda * 2;
  const int swz = ((lane & 7) ^ (lane >> 3)) * 16;
  const char* Ab = (const char*)A + (size_t)(m0 + (lane >> 3)) * ldab + swz;
  auto stageA = [&](int buf, int ks) {
    if (wid < 2)
      gll16(Ab + (size_t)(wid * 8) * ldab + (size_t)ks * 128, SMa + buf * 2048 + wid * 1024);
  };
  stageA(0, 0);
  asm volatile("s_waitcnt vmcnt(0)" ::: "memory");
  __builtin_amdgcn_s_barrier();
  __builtin_amdgcn_sched_barrier(0);
  int cur = 0;
  const int KS8 = KS * 8;
  for (int ks = 0; ks < KS; ks++) {
    if (ks + 1 < KS) stageA(cur ^ 1, ks + 1);
    const f16* sA = (const f16*)(SMa + cur * 2048);
#pragma unroll
    for (int kk = 0; kk < 2; kk++) {
      f16x8 af = *(const f16x8*)(sA + l15 * 64 + (((kk * 4 + l4) ^ (l15 & 7)) * 8));
#pragma unroll
      for (int j = 0; j < 4; j++) {
        const f16* bp = B + ((size_t)(wid * 4 + j) * KS8 + ks * 8 + kk * 4 + l4) * 128 + l15 * 8;
        f16x8 bf = *(const f16x8*)bp;
        acc[j] = __builtin_amdgcn_mfma_f32_16x16x32_f16(af, bf, acc[j], 0, 0, 0);
      }
    }
    asm volatile("s_waitcnt vmcnt(0)" ::: "memory");
    __builtin_amdgcn_sched_barrier(0);
    __builtin_amdgcn_s_barrier();
    cur ^= 1;
  }
  // stage C to LDS
#pragma unroll
  for (int j = 0; j < 4; j++)
#pragma unroll
    for (int r = 0; r < 4; r++)
      SC[(l4 * 4 + r) * 520 + wid * 64 + j * 16 + l15] = acc[j][r];
  __syncthreads();
  // fused row-wise reduction: 8 waves x 2 rows
  const int cbase = lane * 8;
  const float rw = (MODE == 3) ? 0.f : rwv[li];
#pragma unroll
  for (int t = 0; t < 2; t++) {
    const int row = wid * 2 + t, grow = m0 + row;
    f32x4 y0 = *(const f32x4*)(SC + row * 520 + cbase);
    f32x4 y1 = *(const f32x4*)(SC + row * 520 + cbase + 4);
    float y[8];
#pragma unroll
    for (int j = 0; j < 4; j++) { y[j] = y0[j]; y[4 + j] = y1[j]; }
    float trk = 0.f;
    if (MODE == 2) trk = sqrtf(ssq[grow] + 1.f);
    float lss = 0.f, lsu = 0.f;
#pragma unroll
    for (int j = 0; j < 8; j++) {
      int c = cbase + j;
      if (c < 511) {
        y[j] += bias[c];
        if (MODE == 2) y[j] += trk * w0[c];
      } else {
        y[j] = 0.f;
      }
      lss += y[j] * y[j];
      lsu += y[j];
    }
    if (MODE == 3) {
      float s2 = wsum(lss), su = wsum(lsu);
      float mu = su * (1.f / 511.f);
      float var = s2 * (1.f / 511.f) - mu * mu;
      float inv = rsqrtf(var + 1e-5f);
      float n[8], lsn = 0.f;
#pragma unroll
      for (int j = 0; j < 8; j++) {
        int c = cbase + j;
        n[j] = (c < 511) ? ((y[j] - mu) * inv * g[c] + bsh[c]) : 0.f;
        lsn += n[j] * n[j];
      }
      float t2 = sqrtf(wsum(lsn) + 1.f);
      float* orow = outp + (size_t)grow * 512;
      if (lane == 0) orow[0] = t2;
#pragma unroll
      for (int j = 0; j < 8; j++) { int c = cbase + j; if (c < 511) orow[1 + c] = n[j]; }
    } else {
      float tax = sqrtf(wsum(lss) + 1.f);
      const float* xrow = xin + (size_t)grow * 512;
      float xs[8];
#pragma unroll
      for (int j = 0; j < 8; j++) {
        int c = cbase + j;
        xs[j] = (c < 511) ? xrow[1 + c] : 0.f;
      }
      float xt = xrow[0];
      float u[8], lsu2 = 0.f, lsuu = 0.f;
#pragma unroll
      for (int j = 0; j < 8; j++) {
        int c = cbase + j;
        u[j] = (c < 511) ? (xs[j] + rw * y[j]) : 0.f;
        lsuu += u[j]; lsu2 += u[j] * u[j];
      }
      float su = wsum(lsuu), su2 = wsum(lsu2);
      float ut = xt + rw * tax;
      float scp = rsqrtf(fmaxf(ut * ut - su2, 1e-6f));
      float nxt = ut * scp, nx[8];
#pragma unroll
      for (int j = 0; j < 8; j++) nx[j] = u[j] * scp;
      float* xo = xout + (size_t)grow * 512;
      if (lane == 0) xo[0] = nxt;
#pragma unroll
      for (int j = 0; j < 8; j++) { int c = cbase + j; if (c < 511) xo[1 + c] = nx[j]; }
      f16* arow = actW + (size_t)grow * 512;
      if (applyLN) {
        float mu = su * scp * (1.f / 511.f);
        float var = su2 * scp * scp * (1.f / 511.f) - mu * mu;
        float inv = rsqrtf(var + 1e-5f);
        float n[8], lsn = 0.f;
#pragma unroll
        for (int j = 0; j < 8; j++) {
          int c = cbase + j;
          n[j] = (c < 511) ? ((nx[j] - mu) * inv * g[c] + bsh[c]) : 0.f;
          lsn += n[j] * n[j];
        }
        float t2 = sqrtf(wsum(lsn) + 1.f);
        if (lane == 0) arow[0] = (f16)t2;
#pragma unroll
        for (int j = 0; j < 8; j++) { int c = cbase + j; if (c < 511) arow[1 + c] = (f16)n[j]; }
      } else {
        if (lane == 0) arow[0] = (f16)nxt;
#pragma unroll
        for (int j = 0; j < 8; j++) { int c = cbase + j; if (c < 511) arow[1 + c] = (f16)nx[j]; }
      }
      if (MODE == 2 && lane == 0) ssq[grow] = 0.f;
    }
  }
}

// ---------------- merged prologue: weight transposes + embed ----------------
DEV void trans_lin(const float* W, f16* BT, int K, int N, int ldk, int n0, int k0,
                   float* shbuf) {
  float (*tile)[33] = (float(*)[33])shbuf;
  int tx = threadIdx.x & 31, ty = threadIdx.x >> 5;
  for (int i = ty; i < 32; i += 8) {
    int k = k0 + i, n = n0 + tx;
    tile[i][tx] = (k < K && n < N) ? W[(size_t)k * N + n] : 0.f;
  }
  __syncthreads();
  for (int i = ty; i < 32; i += 8)
    BT[(size_t)(n0 + i) * ldk + k0 + tx] = (f16)tile[tx][i];
}

DEV void trans_frag(const float* W, f16* BT, int K, int N, int KS8, int n0, int k0,
                    float* shbuf) {
  float (*tile)[33] = (float(*)[33])shbuf;
  int tx = threadIdx.x & 31, ty = threadIdx.x >> 5;
  for (int i = ty; i < 32; i += 8) {
    int k = k0 + i, n = n0 + tx;
    tile[i][tx] = (k < K && n < N) ? W[(size_t)k * N + n] : 0.f;
  }
  __syncthreads();
  for (int i = ty; i < 32; i += 8)
    BT[fidx(n0 + i, k0 + tx, KS8)] = (f16)tile[tx][i];
}

DEV float block_sum1(float v, float* red) {
#pragma unroll
  for (int o = 32; o; o >>= 1) v += __shfl_xor(v, o);
  int w = threadIdx.x >> 6;
  __syncthreads();
  if ((threadIdx.x & 63) == 0) red[w] = v;
  __syncthreads();
  return red[0] + red[1] + red[2] + red[3];
}

__global__ __launch_bounds__(256)
void k_prolog(const float* __restrict__ Wq, const float* __restrict__ Wk,
              const float* __restrict__ Wv, const float* __restrict__ Wo,
              const float* __restrict__ Wfc, const float* __restrict__ Wpr,
              const float* __restrict__ Wfin,
              f16* __restrict__ wqkvT, f16* __restrict__ woT, f16* __restrict__ wfcT,
              f16* __restrict__ wprT, f16* __restrict__ wfinT,
              const int* __restrict__ tok, const float* __restrict__ etab,
              const float* __restrict__ g, const float* __restrict__ bsh,
              float* __restrict__ x, f16* __restrict__ act, float* __restrict__ ssq) {
  __shared__ float shbuf[32 * 33];
  const int bid = blockIdx.x, tid = threadIdx.x;
  if (bid < 9216) {
    int mat = bid >> 8, tile = bid & 255;
    int layer = mat / 3, typ = mat % 3;
    const float* W = ((typ == 0) ? Wq : (typ == 1) ? Wk : Wv) + (size_t)layer * 262144;
    f16* D = wqkvT + (size_t)layer * 786432 + (size_t)typ * 262144;
    trans_lin(W, D, 512, 512, 512, (tile & 15) * 32, (tile >> 4) * 32, shbuf);
  } else if (bid < 12672) {
    int id = bid - 9216; int l = id / 288, t = id % 288;  // 16 n-tiles x 18 k-tiles
    trans_frag(Wo + (size_t)l * 265720, woT + (size_t)l * 294912, 520, 511, 72,
               (t % 16) * 32, (t / 16) * 32, shbuf);
  } else if (bid < 24960) {
    int id = bid - 12672; int l = id >> 10, t = id & 1023;
    trans_lin(Wfc + (size_t)l * 1048064, wfcT + (size_t)l * 1048576, 512, 2047, 512,
              (t % 64) * 32, (t / 64) * 32, shbuf);
  } else if (bid < 37248) {
    int id = bid - 24960; int l = id >> 10, t = id & 1023;  // 16 n x 64 k
    trans_frag(Wpr + (size_t)l * 1046528 + 511, wprT + (size_t)l * 1048576, 2047, 511, 256,
               (t & 15) * 32, (t >> 4) * 32, shbuf);
  } else if (bid < 37504) {
    int id = bid - 37248;  // 16 n x 16 k
    trans_frag(Wfin, wfinT, 512, 511, 64, (id & 15) * 32, (id >> 4) * 32, shbuf);
  } else {
    float* red = shbuf;
    const int m = bid - 37504;
    const float* e = etab + (size_t)tok[m] * 511;
    float e0 = (tid < 511) ? e[tid] : 0.f;
    float e1 = (tid + 256 < 511) ? e[tid + 256] : 0.f;
    float s1 = block_sum1(e0 + e1, red);
    float s2 = block_sum1(e0 * e0 + e1 * e1, red);
    float t = sqrtf(s2 + 1.f);
    float* xr = x + (size_t)m * 512;
    if (tid == 0) { xr[0] = t; ssq[m] = 0.f; }
    if (tid < 511) xr[1 + tid] = e0;
    if (tid + 256 < 511) xr[257 + tid] = e1;
    float mu = s1 / 511.f;
    float var = s2 / 511.f - mu * mu;
    float inv = rsqrtf(var + 1e-5f);
    float n0 = (tid < 511) ? (e0 - mu) * inv * g[tid] + bsh[tid] : 0.f;
    float n1 = (tid + 256 < 511) ? (e1 - mu) * inv * g[tid + 256] + bsh[tid + 256] : 0.f;
    float sn = block_sum1(n0 * n0 + n1 * n1, red);
    float t2 = sqrtf(sn + 1.f);
    f16* ar = act + (size_t)m * 512;
    if (tid == 0) ar[0] = (f16)t2;
    if (tid < 511) ar[1 + tid] = (f16)n0;
    if (tid + 256 < 511) ar[257 + tid] = (f16)n1;
  }
}

// ---------------- per-wave flash attention + l_project ----------------
__launch_bounds__(64)
__global__ void k_attn(const f16* __restrict__ qhat, const f16* __restrict__ khat,
                       const f16* __restrict__ vT, f16* __restrict__ ao) {
  __shared__ f16 sP[16 * 88];
  const int lin = blockIdx.x;
  const int wg = (lin & 7) * 128 + (lin >> 3);
  const int bh = wg >> 6, rt = 63 - (wg & 63);
  const int lane = threadIdx.x, l15 = lane & 15, l4 = lane >> 4;
  const f16* qp = qhat + ((size_t)bh * 1024 + rt * 16) * 88;
  const f16* kp = khat + (size_t)bh * 1024 * 88;
  const f16* vp = vT + (size_t)bh * 80 * 1024;
  f16x8 qf0 = *(const f16x8*)(qp + l15 * 88 + l4 * 8);
  f16x8 qf1 = *(const f16x8*)(qp + l15 * 88 + 32 + l4 * 8);
  float qth[4];
#pragma unroll
  for (int r = 0; r < 4; r++) qth[r] = (float)qp[(l4 * 4 + r) * 88 + 64];
  f32x4 acc[5];
#pragma unroll
  for (int i = 0; i < 5; i++) acc[i] = (f32x4){0, 0, 0, 0};
  float mrun[4] = {-3e38f, -3e38f, -3e38f, -3e38f}, lrun[4] = {0, 0, 0, 0};
  const int nt = (rt >> 2) + 1;
  for (int jt = 0; jt < nt; ++jt) {
    const int j0 = jt * 64;
    const bool dt = (jt == nt - 1);
    f32x4 sc[4];
#pragma unroll
    for (int fn = 0; fn < 4; fn++) {
      const f16* kb = kp + (size_t)(j0 + fn * 16 + l15) * 88;
      f16x8 k0v = *(const f16x8*)(kb + l4 * 8);
      f16x8 k1v = *(const f16x8*)(kb + 32 + l4 * 8);
      f32x4 a = (f32x4){0, 0, 0, 0};
      a = __builtin_amdgcn_mfma_f32_16x16x32_f16(qf0, k0v, a, 0, 0, 0);
      a = __builtin_amdgcn_mfma_f32_16x16x32_f16(qf1, k1v, a, 0, 0, 0);
      sc[fn] = a;
    }
    float s[4][4];
#pragma unroll
    for (int fn = 0; fn < 4; fn++) {
      float ktc = (float)kp[(size_t)(j0 + fn * 16 + l15) * 88 + 64];
      int col = j0 + fn * 16 + l15;
#pragma unroll
      for (int r = 0; r < 4; r++) {
        int row = rt * 16 + l4 * 4 + r;
        float v = sc[fn][r] - qth[r] * ktc;
        s[fn][r] = (!dt || col <= row) ? v : -3e38f;
      }
    }
    float mnew[4], al[4], rs[4];
#pragma unroll
    for (int r = 0; r < 4; r++) {
      float t = fmaxf(fmaxf(s[0][r], s[1][r]), fmaxf(s[2][r], s[3][r]));
#pragma unroll
      for (int o = 8; o; o >>= 1) t = fmaxf(t, __shfl_xor(t, o));
      mnew[r] = fmaxf(mrun[r], t);
      al[r] = exp2f((mrun[r] - mnew[r]) * 1.44269504f);
      mrun[r] = mnew[r];
      rs[r] = 0.f;
    }
#pragma unroll
    for (int fn = 0; fn < 4; fn++)
#pragma unroll
      for (int r = 0; r < 4; r++) {
        float p = exp2f((s[fn][r] - mnew[r]) * 1.44269504f);
        rs[r] += p;
        sP[(l4 * 4 + r) * 88 + fn * 16 + l15] = (f16)p;
      }
#pragma unroll
    for (int r = 0; r < 4; r++) {
#pragma unroll
      for (int o = 8; o; o >>= 1) rs[r] += __shfl_xor(rs[r], o);
      lrun[r] = lrun[r] * al[r] + rs[r];
    }
#pragma unroll
    for (int fd = 0; fd < 5; fd++)
#pragma unroll
      for (int r = 0; r < 4; r++) acc[fd][r] *= al[r];
    asm volatile("s_waitcnt lgkmcnt(0)" ::: "memory");
    __builtin_amdgcn_sched_barrier(0);
#pragma unroll
    for (int ks = 0; ks < 2; ks++) {
      f16x8 pf = *(const f16x8*)(sP + l15 * 88 + ks * 32 + l4 * 8);
#pragma unroll
      for (int fd = 0; fd < 5; fd++) {
        f16x8 vf = *(const f16x8*)(vp + (size_t)(fd * 16 + l15) * 1024 + j0 + ks * 32 + l4 * 8);
        acc[fd] = __builtin_amdgcn_mfma_f32_16x16x32_f16(pf, vf, acc[fd], 0, 0, 0);
      }
    }
  }
  const int b = bh >> 3, h = bh & 7;
#pragma unroll
  for (int r = 0; r < 4; r++) {
    float invl = 1.0f / lrun[r];
    float ss = 0.f, ov[4];
#pragma unroll
    for (int fd = 0; fd < 4; fd++) { ov[fd] = acc[fd][r] * invl; ss += ov[fd] * ov[fd]; }
#pragma unroll
    for (int o = 8; o; o >>= 1) ss += __shfl_xor(ss, o);
    float tv = acc[4][r] * invl;
    tv = __shfl(tv, lane & 48);
    float scp = rsqrtf(fmaxf(tv * tv - ss, 1e-6f));
    int row = rt * 16 + l4 * 4 + r;
    size_t rowbase = ((size_t)b * 1024 + row) * 576;
    size_t rb = rowbase + h * 65;
    if (l15 == 0) ao[rb] = (f16)(tv * scp);
#pragma unroll
    for (int fd = 0; fd < 4; fd++) ao[rb + 1 + fd * 16 + l15] = (f16)(ov[fd] * scp);
    for (int c = l15; c < 56; c += 16) ao[rowbase + 520 + c] = (f16)0.f;
  }
}

extern "C" void kernel_launch(void* const* d_in, const int* in_sizes, int n_in,
                              void* d_out, int out_size, void* d_ws, size_t ws_size,
                              hipStream_t stream) {
  (void)in_sizes; (void)n_in; (void)out_size; (void)ws_size;
  const int* tok = (const int*)d_in[0];
  const float* etab = (const float*)d_in[1];
  const float* Wq = (const float*)d_in[2];
  const float* bq = (const float*)d_in[3];
  const float* Wk = (const float*)d_in[4];
  const float* bk = (const float*)d_in[5];
  const float* Wv = (const float*)d_in[6];
  const float* bv = (const float*)d_in[7];
  const float* Wo = (const float*)d_in[8];
  const float* bo = (const float*)d_in[9];
  const float* ln1g = (const float*)d_in[10];
  const float* ln1b = (const float*)d_in[11];
  const float* ln2g = (const float*)d_in[12];
  const float* ln2b = (const float*)d_in[13];
  const float* Wfc = (const float*)d_in[14];
  const float* bfc = (const float*)d_in[15];
  const float* Wpr = (const float*)d_in[16];
  const float* bpr = (const float*)d_in[17];
  const float* rw1 = (const float*)d_in[18];
  const float* rw2 = (const float*)d_in[19];
  const float* Wfin = (const float*)d_in[20];
  const float* bfin = (const float*)d_in[21];
  const float* lnfg = (const float*)d_in[22];
  const float* lnfb = (const float*)d_in[23];

  char* wsb = (char*)d_ws;
  size_t off = 0;
  auto alloc = [&](size_t bytes) -> char* {
    char* p = wsb + off;
    off = (off + bytes + 1023) & ~(size_t)1023;
    return p;
  };
  float* xA = (float*)alloc(2048ull * 512 * 4);
  float* xB = (float*)alloc(2048ull * 512 * 4);
  f16* actQ = (f16*)alloc(2048ull * 512 * 2);
  f16* actF = (f16*)alloc(2048ull * 512 * 2);
  float* ssq = (float*)alloc(2048ull * 4);
  f16* qhat = (f16*)alloc(16ull * 1024 * 88 * 2);
  f16* khat = (f16*)alloc(16ull * 1024 * 88 * 2);
  f16* vT = (f16*)alloc(16ull * 80 * 1024 * 2);
  f16* ao = (f16*)alloc(2048ull * 576 * 2);
  f16* fcact = (f16*)alloc(2048ull * 2048 * 2);
  f16* wqkvT = (f16*)alloc(12ull * 786432 * 2);
  f16* woT = (f16*)alloc(12ull * 294912 * 2);
  f16* wfcT = (f16*)alloc(12ull * 1048576 * 2);
  f16* wprT = (f16*)alloc(12ull * 1048576 * 2);
  f16* wfinT = (f16*)alloc(262144ull * 2);

  k_prolog<<<39552, 256, 0, stream>>>(Wq, Wk, Wv, Wo, Wfc, Wpr, Wfin,
                                      wqkvT, woT, wfcT, wprT, wfinT,
                                      tok, etab, ln1g, ln1b, xA, actQ, ssq);

  for (int li = 0; li < 12; li++) {
    const f16* wqkvT_l = wqkvT + (size_t)li * 786432;
    const f16* woT_l = woT + (size_t)li * 294912;
    const f16* wfcT_l = wfcT + (size_t)li * 1048576;
    const f16* wprT_l = wprT + (size_t)li * 1048576;
    const float* Wpr_l = Wpr + (size_t)li * 1046528;  // row 0 = rank-1 weights
    const float* bq_l = bq + (size_t)li * 512;
    const float* bk_l = bk + (size_t)li * 512;
    const float* bv_l = bv + (size_t)li * 512;
    const float* bo_l = bo + (size_t)li * 511;
    const float* bfc_l = bfc + (size_t)li * 2047;
    const float* bpr_l = bpr + (size_t)li * 511;
    const float* ln2g_l = ln2g + (size_t)li * 511;
    const float* ln2b_l = ln2b + (size_t)li * 511;
    const float* ng = (li < 11) ? ln1g + (size_t)(li + 1) * 511 : ln1g;
    const float* nb = (li < 11) ? ln1b + (size_t)(li + 1) * 511 : ln1b;

    k_gemm<1><<<192, 512, 0, stream>>>(actQ, wqkvT_l, 16, bq_l, bk_l, bv_l,
                                       nullptr, qhat, khat, vT);
    k_attn<<<1024, 64, 0, stream>>>(qhat, khat, vT, ao);
    // Wo + fused res1/LN2 -> actF, x: xA -> xB
    k_rowgemm<9, 1><<<128, 512, 0, stream>>>(
        ao, woT_l, 576, bo_l, nullptr, nullptr, xA, xB, ln2g_l, ln2b_l,
        rw1, li, 1, actF, nullptr);
    k_gemm<2><<<256, 512, 0, stream>>>(actF, wfcT_l, 16, bfc_l, nullptr, nullptr,
                                       ssq, fcact, nullptr, nullptr);
    // Wpr + rank-1 + fused res2/LN1(next) -> actQ (or actF for last layer), x: xB -> xA
    k_rowgemm<32, 2><<<128, 512, 0, stream>>>(
        fcact, wprT_l, 2048, bpr_l, Wpr_l, ssq, xB, xA, ng, nb,
        rw2, li, (li < 11) ? 1 : 0, (li < 11) ? actQ : actF, nullptr);
  }

  // Wfin + fused final LN -> out
  k_rowgemm<8, 3><<<128, 512, 0, stream>>>(
      actF, wfinT, 512, bfin, nullptr, nullptr, nullptr, nullptr, lnfg, lnfb,
      nullptr, 0, 0, nullptr, (float*)d_out);
}

// Round 12
// 1608.435 us; speedup vs baseline: 1.4891x; 1.4891x over previous
//
#include <hip/hip_runtime.h>
#include <cstdint>

typedef _Float16 f16;
typedef _Float16 f16x8 __attribute__((ext_vector_type(8)));
typedef float f32x4 __attribute__((ext_vector_type(4)));
typedef unsigned int u32;

#define DEV __device__ __forceinline__

DEV void gll16(const void* g, void* l) {
  __builtin_amdgcn_global_load_lds((const __attribute__((address_space(1))) u32*)g,
                                   (__attribute__((address_space(3))) u32*)l, 16, 0, 0);
}

DEV float block_sum(float v, float* red) {
#pragma unroll
  for (int o = 32; o; o >>= 1) v += __shfl_xor(v, o);
  int w = threadIdx.x >> 6;
  __syncthreads();
  if ((threadIdx.x & 63) == 0) red[w] = v;
  __syncthreads();
  return red[0] + red[1] + red[2] + red[3];
}

// ---------------- GEMM: BK=64, dbuf LDS, raw s_barrier + counted vmcnt ----------------
// EPI 0: O1[row*ldc+col]=acc
// EPI 1: QKV epilogue -> qhat(H1)/khat(H2)/vT(H3)   (BM=128)
// EPI 2: bias+gelu -> H1 f16 [M][2048], atomicAdd ssq (BM=128)
// EPI 3: O(tz) partial; tz==0 adds rank-1 t(ssq)*c0  (BM=64, KZ=4)
template <int BM, int BN, int KZ, int EPI>
__global__ __launch_bounds__((BM == 128) ? 512 : 256)
void k_gemm(const f16* __restrict__ A, const f16* __restrict__ B,
            int lda, int ldb, int klen, int GM,
            float* __restrict__ O1, float* __restrict__ O2,
            float* __restrict__ O3, float* __restrict__ O4, int ldc,
            const float* __restrict__ c0, const float* __restrict__ c1,
            const float* __restrict__ c2, float* __restrict__ ssq,
            f16* __restrict__ H1, f16* __restrict__ H2, f16* __restrict__ H3) {
  constexpr int NW = (BM == 128) ? 8 : 4;      // waves
  constexpr int WM = (BM == 128) ? 4 : 2;      // waves along M
  constexpr int FN = BN / ((NW / WM) * 16);    // col frags per wave
  const int tid = threadIdx.x, wid = tid >> 6, lane = tid & 63;
  const int l15 = lane & 15, l4 = lane >> 4;
  const int wm = wid % WM, wn = wid / WM;
  // XCD-chunked bijective swizzle (gridDim.x % 8 == 0 for all our launches)
  const int nwg = gridDim.x;
  int lin = blockIdx.x;
  int wg = (lin & 7) * (nwg >> 3) + (lin >> 3);
  int tn = wg / (GM * KZ);
  int rem = wg - tn * (GM * KZ);
  int tm = rem / KZ, tz = rem - (rem / KZ) * KZ;
  const int m0 = tm * BM, n0 = tn * BN, kbeg = tz * klen, ksteps = klen / 64;
  __shared__ __align__(16) char SM[(BM + BN) * 256];
  f32x4 acc[2][FN];
#pragma unroll
  for (int i = 0; i < 2; i++)
#pragma unroll
    for (int j = 0; j < FN; j++) acc[i][j] = (f32x4){0.f, 0.f, 0.f, 0.f};
  const size_t ldab = (size_t)lda * 2, ldbb = (size_t)ldb * 2;
  const int swz = ((lane & 7) ^ (lane >> 3)) * 16;
  const char* Ab = (const char*)A + (size_t)(m0 + (lane >> 3)) * ldab + swz + (size_t)kbeg * 2;
  const char* Bb = (const char*)B + (size_t)(n0 + (lane >> 3)) * ldbb + swz + (size_t)kbeg * 2;
  auto stage = [&](int buf, int ks) {  // 4 gll16 per wave
    char* da = SM + buf * (BM * 128);
    char* db = SM + 2 * BM * 128 + buf * (BN * 128);
    for (int i = wid; i < BM / 8; i += NW)
      gll16(Ab + (size_t)(i * 8) * ldab + (size_t)ks * 128, da + i * 1024);
    for (int i = wid; i < BN / 8; i += NW)
      gll16(Bb + (size_t)(i * 8) * ldbb + (size_t)ks * 128, db + i * 1024);
  };
  stage(0, 0);
  asm volatile("s_waitcnt vmcnt(0)" ::: "memory");
  __builtin_amdgcn_s_barrier();
  __builtin_amdgcn_sched_barrier(0);
  int cur = 0;
  for (int ks = 0; ks < ksteps; ks++) {
    const bool more = (ks + 1 < ksteps);
    if (more) {
      stage(cur ^ 1, ks + 1);
      asm volatile("s_waitcnt vmcnt(4)" ::: "memory");  // only cur's 4 loads done
    } else {
      asm volatile("s_waitcnt vmcnt(0)" ::: "memory");
    }
    __builtin_amdgcn_s_barrier();
    __builtin_amdgcn_sched_barrier(0);
    const f16* sA = (const f16*)(SM + cur * (BM * 128));
    const f16* sB = (const f16*)(SM + 2 * BM * 128 + cur * (BN * 128));
#pragma unroll
    for (int kk = 0; kk < 2; kk++) {
      f16x8 af[2], bf[FN];
#pragma unroll
      for (int i = 0; i < 2; i++) {
        int row = wm * 32 + i * 16 + l15;
        af[i] = *(const f16x8*)(sA + row * 64 + (((kk * 4 + l4) ^ (l15 & 7)) * 8));
      }
#pragma unroll
      for (int j = 0; j < FN; j++) {
        int row = wn * (FN * 16) + j * 16 + l15;
        bf[j] = *(const f16x8*)(sB + row * 64 + (((kk * 4 + l4) ^ (l15 & 7)) * 8));
      }
#pragma unroll
      for (int i = 0; i < 2; i++)
#pragma unroll
        for (int j = 0; j < FN; j++)
          acc[i][j] = __builtin_amdgcn_mfma_f32_16x16x32_f16(af[i], bf[j], acc[i][j], 0, 0, 0);
    }
    __builtin_amdgcn_sched_barrier(0);
    __builtin_amdgcn_s_barrier();
    cur ^= 1;
  }
  // ---- epilogues ----
  if (EPI == 0) {
#pragma unroll
    for (int i = 0; i < 2; i++) {
      int row0 = m0 + wm * 32 + i * 16 + l4 * 4;
#pragma unroll
      for (int j = 0; j < FN; j++) {
        int col = n0 + wn * (FN * 16) + j * 16 + l15;
#pragma unroll
        for (int r = 0; r < 4; r++) O1[(size_t)(row0 + r) * ldc + col] = acc[i][j][r];
      }
    }
  } else if (EPI == 1) {
    const int cb = (n0 >> 6) + wn;  // 0..23
    const int typ = cb >> 3, h = cb & 7;
    const float* bb = (typ == 0) ? c0 : (typ == 1) ? c1 : c2;
    float bj[FN];
#pragma unroll
    for (int j = 0; j < FN; j++) bj[j] = bb[h * 64 + j * 16 + l15];
    const float qs = (typ == 0) ? 0.25f : 1.0f;
#pragma unroll
    for (int i = 0; i < 2; i++) {
#pragma unroll
      for (int r = 0; r < 4; r++) {
        float y[FN], ss = 0.f;
#pragma unroll
        for (int j = 0; j < FN; j++) { y[j] = acc[i][j][r] + bj[j]; ss += y[j] * y[j]; }
        ss += __shfl_xor(ss, 1); ss += __shfl_xor(ss, 2);
        ss += __shfl_xor(ss, 4); ss += __shfl_xor(ss, 8);
        float t = sqrtf(ss + 1.f);
        int row = m0 + wm * 32 + i * 16 + l4 * 4 + r;
        int b = row >> 10, s = row & 1023, bh = b * 8 + h;
        if (typ < 2) {
          f16* dst = typ ? H2 : H1;
          size_t base = ((size_t)bh * 1024 + s) * 88;
#pragma unroll
          for (int j = 0; j < FN; j++) dst[base + j * 16 + l15] = (f16)(qs * y[j]);
          if (l15 == 0) dst[base + 64] = (f16)(qs * t);
        } else {
#pragma unroll
          for (int j = 0; j < FN; j++)
            H3[((size_t)bh * 80 + j * 16 + l15) * 1024 + s] = (f16)y[j];
          if (l15 == 0) H3[((size_t)bh * 80 + 64) * 1024 + s] = (f16)t;
        }
      }
    }
  } else if (EPI == 2) {
#pragma unroll
    for (int i = 0; i < 2; i++) {
#pragma unroll
      for (int r = 0; r < 4; r++) {
        int row = m0 + wm * 32 + i * 16 + l4 * 4 + r;
        float ss = 0.f;
#pragma unroll
        for (int j = 0; j < FN; j++) {
          int col = n0 + wn * (FN * 16) + j * 16 + l15;
          float gg = 0.f;
          if (col < 2047) {
            float yv = acc[i][j][r] + c0[col];
            float z = 0.7978845608f * (yv + 0.044715f * yv * yv * yv);
            float th = 1.f - 2.f / (__expf(2.f * z) + 1.f);
            gg = 0.5f * yv * (1.f + th);
          }
          ss += gg * gg;
          H1[(size_t)row * 2048 + col] = (f16)gg;
        }
        ss += __shfl_xor(ss, 1); ss += __shfl_xor(ss, 2);
        ss += __shfl_xor(ss, 4); ss += __shfl_xor(ss, 8);
        if (l15 == 0) atomicAdd(ssq + row, ss);
      }
    }
  } else {  // EPI == 3
    float* O = (tz == 0) ? O1 : (tz == 1) ? O2 : (tz == 2) ? O3 : O4;
#pragma unroll
    for (int i = 0; i < 2; i++) {
#pragma unroll
      for (int r = 0; r < 4; r++) {
        int row = m0 + wm * 32 + i * 16 + l4 * 4 + r;
        float t = 0.f;
        if (tz == 0) t = sqrtf(ssq[row] + 1.f);
#pragma unroll
        for (int j = 0; j < FN; j++) {
          int col = n0 + wn * (FN * 16) + j * 16 + l15;
          float v = acc[i][j][r];
          if (tz == 0) v += t * ((col < 511) ? c0[col] : 0.f);
          O[(size_t)row * ldc + col] = v;
        }
      }
    }
  }
}

// ---------------- merged prologue: all weight transposes + embed ----------------
DEV void trans_tile1(const float* W, f16* BT, int K, int N, int ldk, int n0, int k0,
                     float* shbuf) {
  float (*tile)[33] = (float(*)[33])shbuf;
  int tx = threadIdx.x & 31, ty = threadIdx.x >> 5;
  for (int i = ty; i < 32; i += 8) {
    int k = k0 + i, n = n0 + tx;
    tile[i][tx] = (k < K && n < N) ? W[(size_t)k * N + n] : 0.f;
  }
  __syncthreads();
  for (int i = ty; i < 32; i += 8)
    BT[(size_t)(n0 + i) * ldk + k0 + tx] = (f16)tile[tx][i];
}

__global__ __launch_bounds__(256)
void k_prolog(const float* __restrict__ Wq, const float* __restrict__ Wk,
              const float* __restrict__ Wv, const float* __restrict__ Wo,
              const float* __restrict__ Wfc, const float* __restrict__ Wpr,
              const float* __restrict__ Wfin,
              f16* __restrict__ wqkvT, f16* __restrict__ woT, f16* __restrict__ wfcT,
              f16* __restrict__ wprT, f16* __restrict__ wfinT,
              const int* __restrict__ tok, const float* __restrict__ etab,
              const float* __restrict__ g, const float* __restrict__ bsh,
              float* __restrict__ x, f16* __restrict__ act, float* __restrict__ ssq) {
  __shared__ float shbuf[32 * 33];
  const int bid = blockIdx.x, tid = threadIdx.x;
  if (bid < 9216) {
    int mat = bid >> 8, tile = bid & 255;
    int layer = mat / 3, typ = mat % 3;
    const float* W = ((typ == 0) ? Wq : (typ == 1) ? Wk : Wv) + (size_t)layer * 262144;
    f16* D = wqkvT + (size_t)layer * 786432 + (size_t)typ * 262144;
    trans_tile1(W, D, 512, 512, 512, (tile & 15) * 32, (tile >> 4) * 32, shbuf);
  } else if (bid < 12672) {
    int id = bid - 9216; int l = id / 288, t = id % 288;  // 16 n x 18 k
    trans_tile1(Wo + (size_t)l * 265720, woT + (size_t)l * 294912, 520, 511, 576,
                (t % 16) * 32, (t / 16) * 32, shbuf);
  } else if (bid < 24960) {
    int id = bid - 12672; int l = id >> 10, t = id & 1023;  // 64 n x 16 k
    trans_tile1(Wfc + (size_t)l * 1048064, wfcT + (size_t)l * 1048576, 512, 2047, 512,
                (t % 64) * 32, (t / 64) * 32, shbuf);
  } else if (bid < 37248) {
    int id = bid - 24960; int l = id >> 10, t = id & 1023;  // 16 n x 64 k
    trans_tile1(Wpr + (size_t)l * 1046528 + 511, wprT + (size_t)l * 1048576, 2047, 511, 2048,
                (t & 15) * 32, (t >> 4) * 32, shbuf);
  } else if (bid < 37504) {
    int id = bid - 37248;  // 16 n x 16 k
    trans_tile1(Wfin, wfinT, 512, 511, 512, (id & 15) * 32, (id >> 4) * 32, shbuf);
  } else {
    // embed + add_time + LN1 for one row
    float* red = shbuf;
    const int m = bid - 37504;
    const float* e = etab + (size_t)tok[m] * 511;
    float e0 = (tid < 511) ? e[tid] : 0.f;
    float e1 = (tid + 256 < 511) ? e[tid + 256] : 0.f;
    float s1 = block_sum(e0 + e1, red);
    float s2 = block_sum(e0 * e0 + e1 * e1, red);
    float t = sqrtf(s2 + 1.f);
    float* xr = x + (size_t)m * 512;
    if (tid == 0) { xr[0] = t; ssq[m] = 0.f; }
    if (tid < 511) xr[1 + tid] = e0;
    if (tid + 256 < 511) xr[257 + tid] = e1;
    float mu = s1 / 511.f;
    float var = s2 / 511.f - mu * mu;
    float inv = rsqrtf(var + 1e-5f);
    float n0 = (tid < 511) ? (e0 - mu) * inv * g[tid] + bsh[tid] : 0.f;
    float n1 = (tid + 256 < 511) ? (e1 - mu) * inv * g[tid + 256] + bsh[tid + 256] : 0.f;
    float sn = block_sum(n0 * n0 + n1 * n1, red);
    float t2 = sqrtf(sn + 1.f);
    f16* ar = act + (size_t)m * 512;
    if (tid == 0) ar[0] = (f16)t2;
    if (tid < 511) ar[1 + tid] = (f16)n0;
    if (tid + 256 < 511) ar[257 + tid] = (f16)n1;
  }
}

// ---------------- per-wave flash attention + l_project ----------------
__launch_bounds__(64)
__global__ void k_attn(const f16* __restrict__ qhat, const f16* __restrict__ khat,
                       const f16* __restrict__ vT, f16* __restrict__ ao) {
  __shared__ f16 sP[16 * 88];
  // XCD-chunked: each XCD chunk of 128 blocks = 2 heads, rt heaviest-first
  const int lin = blockIdx.x;
  const int wg = (lin & 7) * 128 + (lin >> 3);
  const int bh = wg >> 6, rt = 63 - (wg & 63);
  const int lane = threadIdx.x, l15 = lane & 15, l4 = lane >> 4;
  const f16* qp = qhat + ((size_t)bh * 1024 + rt * 16) * 88;
  const f16* kp = khat + (size_t)bh * 1024 * 88;
  const f16* vp = vT + (size_t)bh * 80 * 1024;
  f16x8 qf0 = *(const f16x8*)(qp + l15 * 88 + l4 * 8);
  f16x8 qf1 = *(const f16x8*)(qp + l15 * 88 + 32 + l4 * 8);
  float qth[4];
#pragma unroll
  for (int r = 0; r < 4; r++) qth[r] = (float)qp[(l4 * 4 + r) * 88 + 64];
  f32x4 acc[5];
#pragma unroll
  for (int i = 0; i < 5; i++) acc[i] = (f32x4){0, 0, 0, 0};
  float mrun[4] = {-3e38f, -3e38f, -3e38f, -3e38f}, lrun[4] = {0, 0, 0, 0};
  const int nt = (rt >> 2) + 1;
  for (int jt = 0; jt < nt; ++jt) {
    const int j0 = jt * 64;
    const bool dt = (jt == nt - 1);
    f32x4 sc[4];
#pragma unroll
    for (int fn = 0; fn < 4; fn++) {
      const f16* kb = kp + (size_t)(j0 + fn * 16 + l15) * 88;
      f16x8 k0v = *(const f16x8*)(kb + l4 * 8);
      f16x8 k1v = *(const f16x8*)(kb + 32 + l4 * 8);
      f32x4 a = (f32x4){0, 0, 0, 0};
      a = __builtin_amdgcn_mfma_f32_16x16x32_f16(qf0, k0v, a, 0, 0, 0);
      a = __builtin_amdgcn_mfma_f32_16x16x32_f16(qf1, k1v, a, 0, 0, 0);
      sc[fn] = a;
    }
    float s[4][4];
#pragma unroll
    for (int fn = 0; fn < 4; fn++) {
      float ktc = (float)kp[(size_t)(j0 + fn * 16 + l15) * 88 + 64];
      int col = j0 + fn * 16 + l15;
#pragma unroll
      for (int r = 0; r < 4; r++) {
        int row = rt * 16 + l4 * 4 + r;
        float v = sc[fn][r] - qth[r] * ktc;
        s[fn][r] = (!dt || col <= row) ? v : -3e38f;
      }
    }
    float mnew[4], al[4], rs[4];
#pragma unroll
    for (int r = 0; r < 4; r++) {
      float t = fmaxf(fmaxf(s[0][r], s[1][r]), fmaxf(s[2][r], s[3][r]));
#pragma unroll
      for (int o = 8; o; o >>= 1) t = fmaxf(t, __shfl_xor(t, o));
      mnew[r] = fmaxf(mrun[r], t);
      al[r] = exp2f((mrun[r] - mnew[r]) * 1.44269504f);
      mrun[r] = mnew[r];
      rs[r] = 0.f;
    }
#pragma unroll
    for (int fn = 0; fn < 4; fn++)
#pragma unroll
      for (int r = 0; r < 4; r++) {
        float p = exp2f((s[fn][r] - mnew[r]) * 1.44269504f);
        rs[r] += p;
        sP[(l4 * 4 + r) * 88 + fn * 16 + l15] = (f16)p;
      }
#pragma unroll
    for (int r = 0; r < 4; r++) {
#pragma unroll
      for (int o = 8; o; o >>= 1) rs[r] += __shfl_xor(rs[r], o);
      lrun[r] = lrun[r] * al[r] + rs[r];
    }
#pragma unroll
    for (int fd = 0; fd < 5; fd++)
#pragma unroll
      for (int r = 0; r < 4; r++) acc[fd][r] *= al[r];
    asm volatile("s_waitcnt lgkmcnt(0)" ::: "memory");
    __builtin_amdgcn_sched_barrier(0);
#pragma unroll
    for (int ks = 0; ks < 2; ks++) {
      f16x8 pf = *(const f16x8*)(sP + l15 * 88 + ks * 32 + l4 * 8);
#pragma unroll
      for (int fd = 0; fd < 5; fd++) {
        f16x8 vf = *(const f16x8*)(vp + (size_t)(fd * 16 + l15) * 1024 + j0 + ks * 32 + l4 * 8);
        acc[fd] = __builtin_amdgcn_mfma_f32_16x16x32_f16(pf, vf, acc[fd], 0, 0, 0);
      }
    }
  }
  const int b = bh >> 3, h = bh & 7;
#pragma unroll
  for (int r = 0; r < 4; r++) {
    float invl = 1.0f / lrun[r];
    float ss = 0.f, ov[4];
#pragma unroll
    for (int fd = 0; fd < 4; fd++) { ov[fd] = acc[fd][r] * invl; ss += ov[fd] * ov[fd]; }
#pragma unroll
    for (int o = 8; o; o >>= 1) ss += __shfl_xor(ss, o);
    float tv = acc[4][r] * invl;
    tv = __shfl(tv, lane & 48);
    float scp = rsqrtf(fmaxf(tv * tv - ss, 1e-6f));
    int row = rt * 16 + l4 * 4 + r;
    size_t rowbase = ((size_t)b * 1024 + row) * 576;
    size_t rb = rowbase + h * 65;
    if (l15 == 0) ao[rb] = (f16)(tv * scp);
#pragma unroll
    for (int fd = 0; fd < 4; fd++) ao[rb + 1 + fd * 16 + l15] = (f16)(ov[fd] * scp);
    for (int c = l15; c < 56; c += 16) ao[rowbase + 520 + c] = (f16)0.f;
  }
}

// ---------------- residual + l_project (+ optional LN), zeros ssq ----------------
__global__ void k_resproj(float* __restrict__ x, const float* __restrict__ r1,
                          const float* __restrict__ r2, const float* __restrict__ r3,
                          const float* __restrict__ r4, int np,
                          const float* __restrict__ bias, const float* __restrict__ resw, int li,
                          const float* __restrict__ g, const float* __restrict__ bsh,
                          f16* __restrict__ act, int applyLN, float* __restrict__ ssq) {
  __shared__ float red[4];
  const int m = blockIdx.x, tid = threadIdx.x;
  const size_t rb = (size_t)m * 512;
  float* xr = x + rb;
  const float rw = resw[li];
  if (tid == 0) ssq[m] = 0.f;
  float y0 = 0.f, y1 = 0.f;
  if (tid < 511) {
    y0 = r1[rb + tid];
    if (np == 4) y0 += r2[rb + tid] + r3[rb + tid] + r4[rb + tid];
    y0 += bias[tid];
  }
  if (tid + 256 < 511) {
    y1 = r1[rb + tid + 256];
    if (np == 4) y1 += r2[rb + tid + 256] + r3[rb + tid + 256] + r4[rb + tid + 256];
    y1 += bias[tid + 256];
  }
  float s2 = block_sum(y0 * y0 + y1 * y1, red);
  float tax = sqrtf(s2 + 1.f);
  float xt = xr[0];
  float u0 = (tid < 511) ? xr[1 + tid] + rw * y0 : 0.f;
  float u1 = (tid + 256 < 511) ? xr[257 + tid] + rw * y1 : 0.f;
  float ut = xt + rw * tax;
  float su = block_sum(u0 + u1, red);
  float su2 = block_sum(u0 * u0 + u1 * u1, red);
  float scp = rsqrtf(fmaxf(ut * ut - su2, 1e-6f));
  float nx0 = u0 * scp, nx1 = u1 * scp, nxt = ut * scp;
  if (tid == 0) xr[0] = nxt;
  if (tid < 511) xr[1 + tid] = nx0;
  if (tid + 256 < 511) xr[257 + tid] = nx1;
  f16* ar = act + rb;
  if (applyLN) {
    float mu = su * scp / 511.f;
    float var = su2 * scp * scp / 511.f - mu * mu;
    float inv = rsqrtf(var + 1e-5f);
    float n0 = (tid < 511) ? (nx0 - mu) * inv * g[tid] + bsh[tid] : 0.f;
    float n1 = (tid + 256 < 511) ? (nx1 - mu) * inv * g[tid + 256] + bsh[tid + 256] : 0.f;
    float sn = block_sum(n0 * n0 + n1 * n1, red);
    float t2 = sqrtf(sn + 1.f);
    if (tid == 0) ar[0] = (f16)t2;
    if (tid < 511) ar[1 + tid] = (f16)n0;
    if (tid + 256 < 511) ar[257 + tid] = (f16)n1;
  } else {
    if (tid == 0) ar[0] = (f16)nxt;
    if (tid < 511) ar[1 + tid] = (f16)nx0;
    if (tid + 256 < 511) ar[257 + tid] = (f16)nx1;
  }
}

// ---------------- final bias + LN -> out ----------------
__global__ void k_final(const float* __restrict__ raw, const float* __restrict__ bias,
                        const float* __restrict__ g, const float* __restrict__ bsh,
                        float* __restrict__ out) {
  __shared__ float red[4];
  const int m = blockIdx.x, tid = threadIdx.x;
  const float* rr = raw + (size_t)m * 512;
  float y0 = (tid < 511) ? rr[tid] + bias[tid] : 0.f;
  float y1 = (tid + 256 < 511) ? rr[tid + 256] + bias[tid + 256] : 0.f;
  float s1 = block_sum(y0 + y1, red);
  float s2 = block_sum(y0 * y0 + y1 * y1, red);
  float mu = s1 / 511.f;
  float var = s2 / 511.f - mu * mu;
  float inv = rsqrtf(var + 1e-5f);
  float n0 = (tid < 511) ? (y0 - mu) * inv * g[tid] + bsh[tid] : 0.f;
  float n1 = (tid + 256 < 511) ? (y1 - mu) * inv * g[tid + 256] + bsh[tid + 256] : 0.f;
  float sn = block_sum(n0 * n0 + n1 * n1, red);
  float t2 = sqrtf(sn + 1.f);
  float* orow = out + (size_t)m * 512;
  if (tid == 0) orow[0] = t2;
  if (tid < 511) orow[1 + tid] = n0;
  if (tid + 256 < 511) orow[257 + tid] = n1;
}

extern "C" void kernel_launch(void* const* d_in, const int* in_sizes, int n_in,
                              void* d_out, int out_size, void* d_ws, size_t ws_size,
                              hipStream_t stream) {
  (void)in_sizes; (void)n_in; (void)out_size; (void)ws_size;
  const int* tok = (const int*)d_in[0];
  const float* etab = (const float*)d_in[1];
  const float* Wq = (const float*)d_in[2];
  const float* bq = (const float*)d_in[3];
  const float* Wk = (const float*)d_in[4];
  const float* bk = (const float*)d_in[5];
  const float* Wv = (const float*)d_in[6];
  const float* bv = (const float*)d_in[7];
  const float* Wo = (const float*)d_in[8];
  const float* bo = (const float*)d_in[9];
  const float* ln1g = (const float*)d_in[10];
  const float* ln1b = (const float*)d_in[11];
  const float* ln2g = (const float*)d_in[12];
  const float* ln2b = (const float*)d_in[13];
  const float* Wfc = (const float*)d_in[14];
  const float* bfc = (const float*)d_in[15];
  const float* Wpr = (const float*)d_in[16];
  const float* bpr = (const float*)d_in[17];
  const float* rw1 = (const float*)d_in[18];
  const float* rw2 = (const float*)d_in[19];
  const float* Wfin = (const float*)d_in[20];
  const float* bfin = (const float*)d_in[21];
  const float* lnfg = (const float*)d_in[22];
  const float* lnfb = (const float*)d_in[23];

  char* wsb = (char*)d_ws;
  size_t off = 0;
  auto alloc = [&](size_t bytes) -> char* {
    char* p = wsb + off;
    off = (off + bytes + 1023) & ~(size_t)1023;
    return p;
  };
  float* x = (float*)alloc(2048ull * 512 * 4);
  f16* actA = (f16*)alloc(2048ull * 512 * 2);
  float* raw1 = (float*)alloc(2048ull * 512 * 4);
  float* raw2 = (float*)alloc(2048ull * 512 * 4);
  float* raw3 = (float*)alloc(2048ull * 512 * 4);
  float* raw4 = (float*)alloc(2048ull * 512 * 4);
  float* ssq = (float*)alloc(2048ull * 4);
  f16* qhat = (f16*)alloc(16ull * 1024 * 88 * 2);
  f16* khat = (f16*)alloc(16ull * 1024 * 88 * 2);
  f16* vT = (f16*)alloc(16ull * 80 * 1024 * 2);
  f16* ao = (f16*)alloc(2048ull * 576 * 2);
  f16* fcact = (f16*)alloc(2048ull * 2048 * 2);
  f16* wqkvT = (f16*)alloc(12ull * 786432 * 2);
  f16* woT = (f16*)alloc(12ull * 294912 * 2);
  f16* wfcT = (f16*)alloc(12ull * 1048576 * 2);
  f16* wprT = (f16*)alloc(12ull * 1048576 * 2);
  f16* wfinT = (f16*)alloc(512ull * 512 * 2);

  // merged prologue: all weight transposes + embed (1 launch)
  k_prolog<<<39552, 256, 0, stream>>>(Wq, Wk, Wv, Wo, Wfc, Wpr, Wfin,
                                      wqkvT, woT, wfcT, wprT, wfinT,
                                      tok, etab, ln1g, ln1b, x, actA, ssq);

  for (int li = 0; li < 12; li++) {
    const f16* wqkvT_l = wqkvT + (size_t)li * 786432;
    const f16* woT_l = woT + (size_t)li * 294912;
    const f16* wfcT_l = wfcT + (size_t)li * 1048576;
    const f16* wprT_l = wprT + (size_t)li * 1048576;
    const float* Wpr_l = Wpr + (size_t)li * 1046528;
    const float* bq_l = bq + (size_t)li * 512;
    const float* bk_l = bk + (size_t)li * 512;
    const float* bv_l = bv + (size_t)li * 512;
    const float* bo_l = bo + (size_t)li * 511;
    const float* bfc_l = bfc + (size_t)li * 2047;
    const float* bpr_l = bpr + (size_t)li * 511;
    const float* ln2g_l = ln2g + (size_t)li * 511;
    const float* ln2b_l = ln2b + (size_t)li * 511;

    // QKV: M=2048 N=1536 K=512, 128^2, 192 blocks x 512thr
    k_gemm<128, 128, 1, 1><<<192, 512, 0, stream>>>(
        actA, wqkvT_l, 512, 512, 512, 16, nullptr, nullptr, nullptr, nullptr, 0,
        bq_l, bk_l, bv_l, nullptr, qhat, khat, vT);
    k_attn<<<1024, 64, 0, stream>>>(qhat, khat, vT, ao);
    // Wo: M=2048 N=512 K=576, 64^2, 256 blocks
    k_gemm<64, 64, 1, 0><<<256, 256, 0, stream>>>(
        ao, woT_l, 576, 576, 576, 32, raw1, nullptr, nullptr, nullptr, 512,
        nullptr, nullptr, nullptr, nullptr, nullptr, nullptr, nullptr);
    k_resproj<<<2048, 256, 0, stream>>>(x, raw1, raw1, raw1, raw1, 1, bo_l, rw1, li,
                                        ln2g_l, ln2b_l, actA, 1, ssq);
    // FC: M=2048 N=2048 K=512, 128^2, 256 blocks x 512thr
    k_gemm<128, 128, 1, 2><<<256, 512, 0, stream>>>(
        actA, wfcT_l, 512, 512, 512, 16, nullptr, nullptr, nullptr, nullptr, 0,
        bfc_l, nullptr, nullptr, ssq, fcact, nullptr, nullptr);
    // Wpr: M=2048 N=512 K=2048, 64^2, split-K 4, 1024 blocks
    k_gemm<64, 64, 4, 3><<<1024, 256, 0, stream>>>(
        fcact, wprT_l, 2048, 2048, 512, 32, raw1, raw2, raw3, raw4, 512,
        Wpr_l, nullptr, nullptr, ssq, nullptr, nullptr, nullptr);
    const float* ng = (li < 11) ? ln1g + (size_t)(li + 1) * 511 : ln1g;
    const float* nb = (li < 11) ? ln1b + (size_t)(li + 1) * 511 : ln1b;
    k_resproj<<<2048, 256, 0, stream>>>(x, raw1, raw2, raw3, raw4, 4, bpr_l, rw2, li,
                                        ng, nb, actA, (li < 11) ? 1 : 0, ssq);
  }

  k_gemm<64, 64, 1, 0><<<256, 256, 0, stream>>>(
      actA, wfinT, 512, 512, 512, 32, raw1, nullptr, nullptr, nullptr, 512,
      nullptr, nullptr, nullptr, nullptr, nullptr, nullptr, nullptr);
  k_final<<<2048, 256, 0, stream>>>(raw1, bfin, lnfg, lnfb, (float*)d_out);
}